// Round 6
// baseline (276.160 us; speedup 1.0000x reference)
//
#include <hip/hip_runtime.h>
#include <hip/hip_bf16.h>

// SoftMoEGating: B=8, S=4096, D=1024, E=8, P=4, K=E*P=32
#define B 8
#define S 4096
#define DD 1024
#define KK 32

typedef __attribute__((ext_vector_type(8))) short bf16x8;
typedef __attribute__((ext_vector_type(16))) float f32x16;

static __device__ __forceinline__ unsigned short f2bf(float f) {
    unsigned int u = __builtin_bit_cast(unsigned int, f);
    u += 0x7FFFu + ((u >> 16) & 1u);     // RNE
    return (unsigned short)(u >> 16);
}

// ---------------------------------------------------------------------------
// K0: phi [1024 d][32 k] fp32 -> phiT [32 k][1024 d] bf16. grid 32, tiny.
// ---------------------------------------------------------------------------
__global__ __launch_bounds__(256) void k0_phit(const float* __restrict__ phi,
                                               unsigned short* __restrict__ phiT) {
    __shared__ float lt[32][33];
    const int d0 = blockIdx.x * 32;
    const int tid = threadIdx.x;
#pragma unroll
    for (int i = 0; i < 4; ++i) {
        int slot = tid + i * 256;
        int d = slot >> 5, k = slot & 31;
        lt[d][k] = phi[(size_t)(d0 + d) * KK + k];
    }
    __syncthreads();
    const int k = tid >> 3, c = tid & 7, d = c * 4;
    short4 pk;
    pk.x = (short)f2bf(lt[d + 0][k]);
    pk.y = (short)f2bf(lt[d + 1][k]);
    pk.z = (short)f2bf(lt[d + 2][k]);
    pk.w = (short)f2bf(lt[d + 3][k]);
    *(short4*)(phiT + (size_t)k * DD + d0 + d) = pk;
}

// ---------------------------------------------------------------------------
// K1: logits, FULL K=1024 per block (no d-split) via MFMA 32x32x16 bf16.
// grid = 8b x 32 stile(128 s) = 256 (1 block/CU). LDS = x dbuf only
// (2 x [128 s][64 d] bf16 swizzled = 32 KB); phi B-frags read DIRECTLY from
// global phiT (64 KB, L1/L2-hot: 1 KB per b128 frag instr) - no phi staging.
// Epilogue: C -> LDS transpose -> (a) coalesced k-major lp[b][k][s] stores,
// (b) FUSED per-tile softmax stats: pmax/psum[(b,k,stile)] (replaces K2a).
// Bias folded into acc init.
// ---------------------------------------------------------------------------
__global__ __launch_bounds__(256) void k1_logits(const float* __restrict__ x,
                                                 const unsigned short* __restrict__ phiT,
                                                 const float* __restrict__ bias,
                                                 float* __restrict__ lp,
                                                 float* __restrict__ pmax,
                                                 float* __restrict__ psum) {
    __shared__ __align__(16) char sm[32768];

    const int bid = blockIdx.x;
    const int st = bid & 31;
    const int b  = bid >> 5;
    const int s0 = st * 128;
    const int tid = threadIdx.x;
    const int wv = __builtin_amdgcn_readfirstlane(tid >> 6);
    const int lane = tid & 63;
    const int l31 = lane & 31;
    const int half = lane >> 5;

    f32x16 acc;
    {
        float bv = bias[l31];
#pragma unroll
        for (int r = 0; r < 16; ++r) acc[r] = bv;
    }

    const float* xg = x + ((size_t)(b * S + s0)) * DD;

    float4 q[8];
    auto load8 = [&](int ch) {
#pragma unroll
        for (int i = 0; i < 8; ++i) {
            int slot = tid + i * 256;
            int s = slot >> 4, c4 = slot & 15;
            q[i] = *(const float4*)(xg + (size_t)s * DD + ch * 64 + c4 * 4);
        }
    };
    auto store8 = [&](char* buf) {
#pragma unroll
        for (int i = 0; i < 8; ++i) {
            int slot = tid + i * 256;
            int s = slot >> 4, c4 = slot & 15;
            short4 pk;
            pk.x = (short)f2bf(q[i].x);
            pk.y = (short)f2bf(q[i].y);
            pk.z = (short)f2bf(q[i].z);
            pk.w = (short)f2bf(q[i].w);
            *(short4*)(buf + (size_t)s * 128 + (((c4 >> 1) ^ (s & 7)) << 4) + (c4 & 1) * 8) = pk;
        }
    };

    load8(0);
    store8(sm);
    __syncthreads();

    const int srow = wv * 32 + l31;
    const int sx = srow & 7;
    const char* pgb = (const char*)phiT + (size_t)l31 * 2048;  // phi row (k=l31)

    for (int ch = 0; ch < 16; ++ch) {
        char* cur = sm + (ch & 1) * 16384;
        char* nxt = sm + ((ch & 1) ^ 1) * 16384;
        if (ch < 15) load8(ch + 1);
#pragma unroll
        for (int step = 0; step < 4; ++step) {
            int blk = step * 2 + half;
            bf16x8 af  = *(const bf16x8*)(cur + (size_t)srow * 128 + ((blk ^ sx) << 4));
            bf16x8 bfv = *(const bf16x8*)(pgb + ch * 128 + (blk << 4));   // global, L1/L2
            acc = __builtin_amdgcn_mfma_f32_32x32x16_bf16(af, bfv, acc, 0, 0, 0);
        }
        __syncthreads();
        if (ch < 15) store8(nxt);
        __syncthreads();
    }

    // epilogue: C (col=k, row=(r&3)+8*(r>>2)+4*half) -> LDS [32 k][128 s +pad]
    float* lt   = (float*)sm;                 // 32*129*4 = 16512 B
    float* red  = (float*)(sm + 16512);       // 256 floats
    float* sMk  = (float*)(sm + 16512 + 1024);// 32 floats
#pragma unroll
    for (int r = 0; r < 16; ++r) {
        int row = (r & 3) + 8 * (r >> 2) + 4 * half;
        lt[(size_t)l31 * 129 + wv * 32 + row] = acc[r];
    }
    __syncthreads();

    // fused per-tile softmax stats: thread t -> k=t>>3, segment of 16 s
    {
        const int k = tid >> 3, seg = tid & 7;
        const float* row = lt + (size_t)k * 129 + seg * 16;
        float m = row[0];
#pragma unroll
        for (int i = 1; i < 16; ++i) m = fmaxf(m, row[i]);
        red[tid] = m;
        __syncthreads();
        if (tid < 32) {
            float M = red[tid * 8];
#pragma unroll
            for (int j = 1; j < 8; ++j) M = fmaxf(M, red[tid * 8 + j]);
            sMk[tid] = M;
        }
        __syncthreads();
        float M = sMk[k];
        float l = 0.f;
#pragma unroll
        for (int i = 0; i < 16; ++i) l += __expf(row[i] - M);
        red[tid] = l;
        __syncthreads();
        if (tid < 32) {
            float L = 0.f;
#pragma unroll
            for (int j = 0; j < 8; ++j) L += red[tid * 8 + j];
            pmax[((size_t)b * KK + tid) * 32 + st] = sMk[tid];
            psum[((size_t)b * KK + tid) * 32 + st] = L;
        }
    }

    // coalesced k-major logit stores lp[b][k][s]
    float* o = lp + ((size_t)b * KK) * S + s0;
#pragma unroll
    for (int i = 0; i < 4; ++i) {
        int slot = tid + i * 256;
        int k = slot >> 5, s4 = slot & 31;
        float4 v;
        v.x = lt[k * 129 + s4 * 4 + 0];
        v.y = lt[k * 129 + s4 * 4 + 1];
        v.z = lt[k * 129 + s4 * 4 + 2];
        v.w = lt[k * 129 + s4 * 4 + 3];
        *(float4*)(o + (size_t)k * S + s4 * 4) = v;
    }
}

// ---------------------------------------------------------------------------
// K2c: combine 32 tile-stats per (b,k) -> (M, 1/L); normalize lp; write wbT
// bf16 [b][k][s] (K3's A-operand, coalesced) AND d_out's [b][s][k] fp32 via
// LDS transpose. grid = B*32 (s-chunks of 128).
// ---------------------------------------------------------------------------
__global__ __launch_bounds__(256) void k2c_norm(const float* __restrict__ lp,
                                                const float* __restrict__ pmax,
                                                const float* __restrict__ psum,
                                                unsigned short* __restrict__ wbT,
                                                float* __restrict__ pw_out) {
    __shared__ float tile[128][33];
    __shared__ float sM[32], sLinv[32];
    const int b  = blockIdx.x >> 5;
    const int sc = blockIdx.x & 31;
    const int s0 = sc * 128;
    const int tid = threadIdx.x;

    if (tid < 32) {
        const int k = tid;
        float M = -1e30f, L = 0.f;
#pragma unroll
        for (int c = 0; c < 32; ++c) {
            float mc = pmax[((size_t)b * KK + k) * 32 + c];
            float lc = psum[((size_t)b * KK + k) * 32 + c];
            float nM = fmaxf(M, mc);
            L = L * __expf(M - nM) + lc * __expf(mc - nM);
            M = nM;
        }
        sM[k] = M;
        sLinv[k] = 1.0f / L;
    }
    __syncthreads();

    const int sL = tid & 127;
    const int kh = tid >> 7;
#pragma unroll
    for (int kk = 0; kk < 16; ++kk) {
        const int k = kk * 2 + kh;
        const size_t idx = ((size_t)b * KK + k) * S + s0 + sL;
        float w = __expf(lp[idx] - sM[k]) * sLinv[k];
        wbT[idx] = f2bf(w);
        tile[sL][k] = w;
    }
    __syncthreads();

    float* ob = pw_out + ((size_t)b * S + s0) * KK;
#pragma unroll
    for (int i = 0; i < 4; ++i) {
        const int idx4 = tid + i * 256;
        const int sl = idx4 >> 3, kq = idx4 & 7;
        float4 v4 = make_float4(tile[sl][kq * 4 + 0], tile[sl][kq * 4 + 1],
                                tile[sl][kq * 4 + 2], tile[sl][kq * 4 + 3]);
        ((float4*)ob)[idx4] = v4;
    }
}

// ---------------------------------------------------------------------------
// K3: soft_slots via MFMA: C[k][d] = sum_s w[k][s] x[s][d].
// grid = 8b x 8 dgroup(128 d) x 8 sc(512 s) = 512 (2 blocks/CU). LDS = xT dbuf
// only (2 x [128 d][64 s] bf16 = 32 KB, transpose-staged); w A-frags read
// DIRECTLY from global wbT (2 MB, L2-hot). part[sc][b][k][d] fp32.
// ---------------------------------------------------------------------------
__global__ __launch_bounds__(256) void k3_slots(const float* __restrict__ x,
                                                const unsigned short* __restrict__ wbT,
                                                float* __restrict__ part) {
    __shared__ __align__(16) char sm[32768];

    const int bid = blockIdx.x;
    const int sc = bid & 7;
    const int dg = (bid >> 3) & 7;
    const int b  = bid >> 6;
    const int tid = threadIdx.x;
    const int wv = __builtin_amdgcn_readfirstlane(tid >> 6);
    const int lane = tid & 63;
    const int l31 = lane & 31;
    const int half = lane >> 5;

    const int dth = tid & 127;      // staging: d lane
    const int sh  = tid >> 7;       // staging: s-half

    const float* xg = x + ((size_t)(b * S + sc * 512)) * DD + dg * 128 + dth;

    float q0[16], q1[16];
    auto loadc = [&](int ch) {
#pragma unroll
        for (int j = 0; j < 16; ++j) {
            int sp = sh * 16 + j;
            q0[j] = xg[(size_t)(ch * 64 + sp * 2) * DD];
            q1[j] = xg[(size_t)(ch * 64 + sp * 2 + 1) * DD];
        }
    };
    auto storec = [&](char* xB) {
#pragma unroll
        for (int j = 0; j < 16; ++j) {
            int sp = sh * 16 + j;
            unsigned int pkd = (unsigned int)f2bf(q0[j]) | ((unsigned int)f2bf(q1[j]) << 16);
            *(unsigned int*)(xB + (size_t)dth * 128 + (((sp >> 2) ^ (dth & 7)) << 4) + (sp & 3) * 4) = pkd;
        }
    };

    f32x16 acc;
#pragma unroll
    for (int r = 0; r < 16; ++r) acc[r] = 0.f;

    loadc(0);
    storec(sm);
    __syncthreads();

    const int dloc = wv * 32 + l31;
    const int dx = dloc & 7;
    const char* wgb = (const char*)wbT + ((size_t)(b * KK + l31) * S + sc * 512) * 2;

    for (int ch = 0; ch < 8; ++ch) {
        char* cur = sm + (ch & 1) * 16384;
        char* nxt = sm + ((ch & 1) ^ 1) * 16384;
        if (ch < 7) loadc(ch + 1);
#pragma unroll
        for (int step = 0; step < 4; ++step) {
            int blk = step * 2 + half;
            bf16x8 af  = *(const bf16x8*)(wgb + ch * 128 + (blk << 4));   // global, L2
            bf16x8 bfv = *(const bf16x8*)(cur + (size_t)dloc * 128 + ((blk ^ dx) << 4));
            acc = __builtin_amdgcn_mfma_f32_32x32x16_bf16(af, bfv, acc, 0, 0, 0);
        }
        __syncthreads();
        if (ch < 7) storec(nxt);
        __syncthreads();
    }

    float* pp = part + (((size_t)sc * B + b) * KK) * DD + dg * 128 + wv * 32 + l31;
#pragma unroll
    for (int r = 0; r < 16; ++r) {
        int k = (r & 3) + 8 * (r >> 2) + 4 * half;
        pp[(size_t)k * DD] = acc[r];
    }
}

// ---------------------------------------------------------------------------
// K4: reduce 8 partials -> soft_slots + expert_inputs; fill expert_weights
// (0.125) and expert_indices (0..7). grid 256.
// ---------------------------------------------------------------------------
__global__ __launch_bounds__(256) void k4_finalize(const float* __restrict__ part,
                                                   float* __restrict__ out) {
    const int idx = blockIdx.x * 256 + threadIdx.x;
    const float4* p4 = (const float4*)part;

    float4 sv = p4[idx];
#pragma unroll
    for (int c = 1; c < 8; ++c) {
        float4 t = p4[(size_t)c * 65536 + idx];
        sv.x += t.x; sv.y += t.y; sv.z += t.z; sv.w += t.w;
    }

    // out floats: ew[0..262144) ei[262144..524288) pw[524288..1572864)
    //             ss[1572864..1835008) einp[1835008..2097152)
    ((float4*)(out + 1572864))[idx] = sv;
    ((float4*)(out + 1835008))[idx] = sv;
    ((float4*)out)[idx] = make_float4(0.125f, 0.125f, 0.125f, 0.125f);
    float base = (float)((idx * 4) & 7);
    ((float4*)(out + 262144))[idx] = make_float4(base, base + 1.f, base + 2.f, base + 3.f);
}

extern "C" void kernel_launch(void* const* d_in, const int* in_sizes, int n_in,
                              void* d_out, int out_size, void* d_ws, size_t ws_size,
                              hipStream_t stream) {
    const float* x    = (const float*)d_in[0];
    const float* phi  = (const float*)d_in[1];
    const float* bias = (const float*)d_in[2];
    float* out = (float*)d_out;

    // ws layout (float units):
    //   lp    @ 0        (1048576 = 4 MB, [b][k][s], full logits)
    //   pmax  @ 1048576  (8192: per (b,k,stile32))
    //   psum  @ 1056768  (8192)
    //   wbT   @ 1064960  (1048576 u16 = 524288 f)
    //   phiT  @ 1589248  (32768 u16 = 16384 f)
    //   part  @ 1605632  (8 x 262144)
    float* ws = (float*)d_ws;
    float* lp   = ws;
    float* pmax = ws + 1048576;
    float* psum = ws + 1056768;
    unsigned short* wbT  = (unsigned short*)(ws + 1064960);
    unsigned short* phiT = (unsigned short*)(ws + 1589248);
    float* part = ws + 1605632;
    float* pw_out = out + 524288;

    k0_phit<<<dim3(32), dim3(256), 0, stream>>>(phi, phiT);
    k1_logits<<<dim3(256), dim3(256), 0, stream>>>(x, phiT, bias, lp, pmax, psum);
    k2c_norm<<<dim3(256), dim3(256), 0, stream>>>(lp, pmax, psum, wbT, pw_out);
    k3_slots<<<dim3(512), dim3(256), 0, stream>>>(x, wbT, part);
    k4_finalize<<<dim3(256), dim3(256), 0, stream>>>(part, out);
}

// Round 7
// 239.992 us; speedup vs baseline: 1.1507x; 1.1507x over previous
//
#include <hip/hip_runtime.h>
#include <hip/hip_bf16.h>

// SoftMoEGating: B=8, S=4096, D=1024, E=8, P=4, K=E*P=32
#define B 8
#define S 4096
#define DD 1024
#define KK 32

typedef __attribute__((ext_vector_type(8))) short bf16x8;
typedef __attribute__((ext_vector_type(16))) float f32x16;

static __device__ __forceinline__ unsigned short f2bf(float f) {
    unsigned int u = __builtin_bit_cast(unsigned int, f);
    u += 0x7FFFu + ((u >> 16) & 1u);     // RNE
    return (unsigned short)(u >> 16);
}

// ---------------------------------------------------------------------------
// K0: phi [1024 d][32 k] fp32 -> phiT [32 k][1024 d] bf16. grid 32, tiny.
// ---------------------------------------------------------------------------
__global__ __launch_bounds__(256) void k0_phit(const float* __restrict__ phi,
                                               unsigned short* __restrict__ phiT) {
    __shared__ float lt[32][33];
    const int d0 = blockIdx.x * 32;
    const int tid = threadIdx.x;
#pragma unroll
    for (int i = 0; i < 4; ++i) {
        int slot = tid + i * 256;
        int d = slot >> 5, k = slot & 31;
        lt[d][k] = phi[(size_t)(d0 + d) * KK + k];
    }
    __syncthreads();
    const int k = tid >> 3, c = tid & 7, d = c * 4;
    short4 pk;
    pk.x = (short)f2bf(lt[d + 0][k]);
    pk.y = (short)f2bf(lt[d + 1][k]);
    pk.z = (short)f2bf(lt[d + 2][k]);
    pk.w = (short)f2bf(lt[d + 3][k]);
    *(short4*)(phiT + (size_t)k * DD + d0 + d) = pk;
}

// ---------------------------------------------------------------------------
// K1: partial logits, DSPLIT=4 (K=256/block) via MFMA 32x32x16 bf16.
// grid = 8b x 32 stile(128 s) x 4 dq = 1024 (4 blocks/CU, 16 waves/CU).
// LDS = x dbuf only (2 x [128 s][64 d] bf16 swizzled = 32 KB). phi B-frags
// REGISTER-PREFETCHED from global (L1-hot, issued with next x load8 so the
// MFMA block never drains vmcnt). Epilogue: C -> LDS transpose -> coalesced
// k-major partial stores lp[dq][b][k][s]. Bias folded in at dq==0.
// ---------------------------------------------------------------------------
__global__ __launch_bounds__(256) void k1_logits(const float* __restrict__ x,
                                                 const unsigned short* __restrict__ phiT,
                                                 const float* __restrict__ bias,
                                                 float* __restrict__ lp) {
    __shared__ __align__(16) char sm[32768];

    const int bid = blockIdx.x;
    const int dq = bid & 3;
    const int st = (bid >> 2) & 31;
    const int b  = bid >> 7;
    const int s0 = st * 128;
    const int tid = threadIdx.x;
    const int wv = __builtin_amdgcn_readfirstlane(tid >> 6);
    const int lane = tid & 63;
    const int l31 = lane & 31;
    const int half = lane >> 5;

    f32x16 acc;
    {
        float bv = (dq == 0) ? bias[l31] : 0.f;
#pragma unroll
        for (int r = 0; r < 16; ++r) acc[r] = bv;
    }

    const float* xg = x + ((size_t)(b * S + s0)) * DD + dq * 256;
    const char* pgb = (const char*)phiT + (size_t)l31 * 2048 + dq * 512;

    float4 q[8];
    auto load8 = [&](int ch) {
#pragma unroll
        for (int i = 0; i < 8; ++i) {
            int slot = tid + i * 256;
            int s = slot >> 4, c4 = slot & 15;
            q[i] = *(const float4*)(xg + (size_t)s * DD + ch * 64 + c4 * 4);
        }
    };
    auto store8 = [&](char* buf) {
#pragma unroll
        for (int i = 0; i < 8; ++i) {
            int slot = tid + i * 256;
            int s = slot >> 4, c4 = slot & 15;
            short4 pk;
            pk.x = (short)f2bf(q[i].x);
            pk.y = (short)f2bf(q[i].y);
            pk.z = (short)f2bf(q[i].z);
            pk.w = (short)f2bf(q[i].w);
            *(short4*)(buf + (size_t)s * 128 + (((c4 >> 1) ^ (s & 7)) << 4) + (c4 & 1) * 8) = pk;
        }
    };

    bf16x8 pf[4];
    auto loadphi = [&](bf16x8* dst, int ch) {
#pragma unroll
        for (int t = 0; t < 4; ++t)
            dst[t] = *(const bf16x8*)(pgb + ch * 128 + (((t * 2 + half)) << 4));
    };

    load8(0);
    loadphi(pf, 0);
    store8(sm);
    __syncthreads();

    const int srow = wv * 32 + l31;
    const int sx = srow & 7;

#pragma unroll
    for (int ch = 0; ch < 4; ++ch) {
        char* cur = sm + (ch & 1) * 16384;
        char* nxt = sm + ((ch & 1) ^ 1) * 16384;
        bf16x8 npf[4];
        if (ch < 3) {
            load8(ch + 1);       // x prefetch (global)
            loadphi(npf, ch + 1);// phi prefetch (global, L1-hot)
        }
#pragma unroll
        for (int step = 0; step < 4; ++step) {
            int blk = step * 2 + half;
            bf16x8 af = *(const bf16x8*)(cur + (size_t)srow * 128 + ((blk ^ sx) << 4));
            acc = __builtin_amdgcn_mfma_f32_32x32x16_bf16(af, pf[step], acc, 0, 0, 0);
        }
        __syncthreads();
        if (ch < 3) {
            store8(nxt);
#pragma unroll
            for (int t = 0; t < 4; ++t) pf[t] = npf[t];
        }
        __syncthreads();
    }

    // epilogue: C (col=k, row=(r&3)+8*(r>>2)+4*half) -> LDS [32 k][128 s +pad]
    float* lt = (float*)sm;   // 32*129*4 = 16512 B
#pragma unroll
    for (int r = 0; r < 16; ++r) {
        int row = (r & 3) + 8 * (r >> 2) + 4 * half;
        lt[(size_t)l31 * 129 + wv * 32 + row] = acc[r];
    }
    __syncthreads();

    float* o = lp + (size_t)dq * (B * KK * S) + ((size_t)b * KK) * S + s0;
#pragma unroll
    for (int i = 0; i < 4; ++i) {
        int slot = tid + i * 256;
        int k = slot >> 5, s4 = slot & 31;
        float4 v;
        v.x = lt[k * 129 + s4 * 4 + 0];
        v.y = lt[k * 129 + s4 * 4 + 1];
        v.z = lt[k * 129 + s4 * 4 + 2];
        v.w = lt[k * 129 + s4 * 4 + 3];
        *(float4*)(o + (size_t)k * S + s4 * 4) = v;
    }
}

// ---------------------------------------------------------------------------
// K2a: per (b,k, s-chunk 512): partial max + sum of exp over the 4-partial
// sum. grid 2048 (8 blocks/CU).
// ---------------------------------------------------------------------------
__global__ __launch_bounds__(256) void k2a_partial(const float* __restrict__ lp,
                                                   float* __restrict__ pmax,
                                                   float* __restrict__ psum) {
    const int bid = blockIdx.x;
    const int c  = bid & 7;
    const int bk = bid >> 3;
    const int tid = threadIdx.x;
    const int wave = tid >> 6, lane = tid & 63;
    const size_t base = (size_t)bk * S + c * 512;

    float v0 = 0.f, v1 = 0.f;
#pragma unroll
    for (int p = 0; p < 4; ++p) {
        v0 += lp[(size_t)p * 1048576 + base + tid];
        v1 += lp[(size_t)p * 1048576 + base + tid + 256];
    }

    float m = fmaxf(v0, v1);
#pragma unroll
    for (int off = 32; off >= 1; off >>= 1) m = fmaxf(m, __shfl_xor(m, off, 64));
    __shared__ float sm_[4], sl[4];
    if (lane == 0) sm_[wave] = m;
    __syncthreads();
    const float M = fmaxf(fmaxf(sm_[0], sm_[1]), fmaxf(sm_[2], sm_[3]));

    float l = __expf(v0 - M) + __expf(v1 - M);
#pragma unroll
    for (int off = 32; off >= 1; off >>= 1) l += __shfl_xor(l, off, 64);
    if (lane == 0) sl[wave] = l;
    __syncthreads();
    if (tid == 0) {
        pmax[bid] = M;
        psum[bid] = sl[0] + sl[1] + sl[2] + sl[3];
    }
}

// ---------------------------------------------------------------------------
// K2c: combine 8 chunk-stats -> (M, 1/L); sum 4 lp partials; normalize; write
// wbT bf16 [b][k][s] (K3 A-operand, coalesced) AND d_out [b][s][k] fp32 via
// LDS transpose. grid = B*64 (s-chunks of 64), 2 blocks/CU.
// ---------------------------------------------------------------------------
__global__ __launch_bounds__(256) void k2c_norm(const float* __restrict__ lp,
                                                const float* __restrict__ pmax,
                                                const float* __restrict__ psum,
                                                unsigned short* __restrict__ wbT,
                                                float* __restrict__ pw_out) {
    __shared__ float tile[64][33];
    __shared__ float sM[32], sLinv[32];
    const int b  = blockIdx.x >> 6;
    const int sc = blockIdx.x & 63;
    const int s0 = sc * 64;
    const int tid = threadIdx.x;

    if (tid < 32) {
        const int k = tid;
        float M = -1e30f, L = 0.f;
#pragma unroll
        for (int c = 0; c < 8; ++c) {
            float mc = pmax[(b * KK + k) * 8 + c];
            float lc = psum[(b * KK + k) * 8 + c];
            float nM = fmaxf(M, mc);
            L = L * __expf(M - nM) + lc * __expf(mc - nM);
            M = nM;
        }
        sM[k] = M;
        sLinv[k] = 1.0f / L;
    }
    __syncthreads();

    const int sL = tid & 63;
    const int kh = tid >> 6;   // 0..3
#pragma unroll
    for (int kk = 0; kk < 8; ++kk) {
        const int k = kk * 4 + kh;
        const size_t idx = ((size_t)b * KK + k) * S + s0 + sL;
        float v = 0.f;
#pragma unroll
        for (int p = 0; p < 4; ++p) v += lp[(size_t)p * 1048576 + idx];
        float w = __expf(v - sM[k]) * sLinv[k];
        wbT[idx] = f2bf(w);
        tile[sL][k] = w;
    }
    __syncthreads();

    float* ob = pw_out + ((size_t)b * S + s0) * KK;
#pragma unroll
    for (int i = 0; i < 2; ++i) {
        const int idx4 = tid + i * 256;          // 0..511 float4 slots
        const int sl = idx4 >> 3, kq = idx4 & 7;
        float4 v4 = make_float4(tile[sl][kq * 4 + 0], tile[sl][kq * 4 + 1],
                                tile[sl][kq * 4 + 2], tile[sl][kq * 4 + 3]);
        ((float4*)ob)[idx4] = v4;
    }
}

// ---------------------------------------------------------------------------
// K3: partial soft_slots via MFMA: C[k][d] = sum_s w[k][s] x[s][d].
// grid = 8b x 8 dgroup(128 d) x 16 sc(256 s) = 1024 (4 blocks/CU).
// LDS = xT dbuf (2 x [128 d][64 s] bf16 = 32 KB, transpose-staged with
// lane-coalesced fp32 loads). w A-frags REGISTER-PREFETCHED from global wbT
// (L2-hot). part[sc][b][k][d] fp32.
// ---------------------------------------------------------------------------
__global__ __launch_bounds__(256) void k3_slots(const float* __restrict__ x,
                                                const unsigned short* __restrict__ wbT,
                                                float* __restrict__ part) {
    __shared__ __align__(16) char sm[32768];

    const int bid = blockIdx.x;
    const int sc = bid & 15;
    const int dg = (bid >> 4) & 7;
    const int b  = bid >> 7;
    const int tid = threadIdx.x;
    const int wv = __builtin_amdgcn_readfirstlane(tid >> 6);
    const int lane = tid & 63;
    const int l31 = lane & 31;
    const int half = lane >> 5;

    const int dth = tid & 127;      // staging: d lane
    const int sh  = tid >> 7;       // staging: s-half

    const float* xg = x + ((size_t)(b * S + sc * 256)) * DD + dg * 128 + dth;
    const char* wgb = (const char*)wbT + ((size_t)(b * KK + l31) * S + sc * 256) * 2;

    float q0[16], q1[16];
    auto loadc = [&](int ch) {
#pragma unroll
        for (int j = 0; j < 16; ++j) {
            int sp = sh * 16 + j;
            q0[j] = xg[(size_t)(ch * 64 + sp * 2) * DD];
            q1[j] = xg[(size_t)(ch * 64 + sp * 2 + 1) * DD];
        }
    };
    auto storec = [&](char* xB) {
#pragma unroll
        for (int j = 0; j < 16; ++j) {
            int sp = sh * 16 + j;
            unsigned int pkd = (unsigned int)f2bf(q0[j]) | ((unsigned int)f2bf(q1[j]) << 16);
            *(unsigned int*)(xB + (size_t)dth * 128 + (((sp >> 2) ^ (dth & 7)) << 4) + (sp & 3) * 4) = pkd;
        }
    };
    bf16x8 wf[4];
    auto loadw = [&](bf16x8* dst, int ch) {
#pragma unroll
        for (int t = 0; t < 4; ++t)
            dst[t] = *(const bf16x8*)(wgb + ch * 128 + ((t * 2 + half) << 4));
    };

    f32x16 acc;
#pragma unroll
    for (int r = 0; r < 16; ++r) acc[r] = 0.f;

    loadc(0);
    loadw(wf, 0);
    storec(sm);
    __syncthreads();

    const int dloc = wv * 32 + l31;
    const int dx = dloc & 7;

#pragma unroll
    for (int ch = 0; ch < 4; ++ch) {
        char* cur = sm + (ch & 1) * 16384;
        char* nxt = sm + ((ch & 1) ^ 1) * 16384;
        bf16x8 nwf[4];
        if (ch < 3) {
            loadc(ch + 1);
            loadw(nwf, ch + 1);
        }
#pragma unroll
        for (int step = 0; step < 4; ++step) {
            int blk = step * 2 + half;
            bf16x8 bfv = *(const bf16x8*)(cur + (size_t)dloc * 128 + ((blk ^ dx) << 4));
            acc = __builtin_amdgcn_mfma_f32_32x32x16_bf16(wf[step], bfv, acc, 0, 0, 0);
        }
        __syncthreads();
        if (ch < 3) {
            storec(nxt);
#pragma unroll
            for (int t = 0; t < 4; ++t) wf[t] = nwf[t];
        }
        __syncthreads();
    }

    float* pp = part + (((size_t)sc * B + b) * KK) * DD + dg * 128 + wv * 32 + l31;
#pragma unroll
    for (int r = 0; r < 16; ++r) {
        int k = (r & 3) + 8 * (r >> 2) + 4 * half;
        pp[(size_t)k * DD] = acc[r];
    }
}

// ---------------------------------------------------------------------------
// K4: reduce 16 partials -> soft_slots + expert_inputs; fill expert_weights
// (0.125) and expert_indices (0..7). float2 granularity, grid 512 (2 blk/CU).
// ---------------------------------------------------------------------------
__global__ __launch_bounds__(256) void k4_finalize(const float* __restrict__ part,
                                                   float* __restrict__ out) {
    const int idx = blockIdx.x * 256 + threadIdx.x;  // 0..131071 float2 slots
    const float2* p2 = (const float2*)part;

    float2 sv = p2[idx];
#pragma unroll
    for (int c = 1; c < 16; ++c) {
        float2 t = p2[(size_t)c * 131072 + idx];
        sv.x += t.x; sv.y += t.y;
    }

    // out floats: ew[0..262144) ei[262144..524288) pw[524288..1572864)
    //             ss[1572864..1835008) einp[1835008..2097152)
    ((float2*)(out + 1572864))[idx] = sv;
    ((float2*)(out + 1835008))[idx] = sv;
    ((float2*)out)[idx] = make_float2(0.125f, 0.125f);
    float e0 = (float)((idx * 2) & 7);
    ((float2*)(out + 262144))[idx] = make_float2(e0, e0 + 1.f);
}

extern "C" void kernel_launch(void* const* d_in, const int* in_sizes, int n_in,
                              void* d_out, int out_size, void* d_ws, size_t ws_size,
                              hipStream_t stream) {
    const float* x    = (const float*)d_in[0];
    const float* phi  = (const float*)d_in[1];
    const float* bias = (const float*)d_in[2];
    float* out = (float*)d_out;

    // ws layout (float units):
    //   lp    @ 0        (4 x 1048576 = 16 MB, [dq][b][k][s])
    //   pmax  @ 4194304  (2048)
    //   psum  @ 4196352  (2048)
    //   wbT   @ 4198400  (1048576 u16 = 524288 f)
    //   phiT  @ 4722688  (32768 u16 = 16384 f)
    //   part  @ 4739072  (16 x 262144 = 16 MB)
    float* ws = (float*)d_ws;
    float* lp   = ws;
    float* pmax = ws + 4194304;
    float* psum = ws + 4196352;
    unsigned short* wbT  = (unsigned short*)(ws + 4198400);
    unsigned short* phiT = (unsigned short*)(ws + 4722688);
    float* part = ws + 4739072;
    float* pw_out = out + 524288;

    k0_phit<<<dim3(32), dim3(256), 0, stream>>>(phi, phiT);
    k1_logits<<<dim3(1024), dim3(256), 0, stream>>>(x, phiT, bias, lp);
    k2a_partial<<<dim3(2048), dim3(256), 0, stream>>>(lp, pmax, psum);
    k2c_norm<<<dim3(512), dim3(256), 0, stream>>>(lp, pmax, psum, wbT, pw_out);
    k3_slots<<<dim3(1024), dim3(256), 0, stream>>>(x, wbT, part);
    k4_finalize<<<dim3(512), dim3(256), 0, stream>>>(part, out);
}